// Round 1
// baseline (1525.407 us; speedup 1.0000x reference)
//
#include <hip/hip_runtime.h>
#include <hip/hip_bf16.h>

typedef unsigned int  uint32;
typedef unsigned short ushort16;

#define B_TOTAL 65536
#define NN 17

// ---- fixed normalized adjacency (from EDGES in the reference) ----
static constexpr int   CNT[NN]    = {2,0,0,0,0,4,4,2,2,1,1,3,3,2,2,1,1};
static constexpr int   NBR[NN][4] = {
  {5,6,0,0},{0,0,0,0},{0,0,0,0},{0,0,0,0},{0,0,0,0},
  {7,6,11,0},{8,5,12,0},{5,9,0,0},{6,10,0,0},{7,0,0,0},{8,0,0,0},
  {5,12,13,0},{6,11,14,0},{11,15,0,0},{12,16,0,0},{13,0,0,0},{14,0,0,0}};
static constexpr float INVDEG[NN] = {0.5f,0.f,0.f,0.f,0.f,0.25f,0.25f,0.5f,0.5f,1.f,1.f,
  0.33333333333333333f,0.33333333333333333f,0.5f,0.5f,1.f,1.f};

// ---- workspace layout (bytes) ----
//  S      : bf16 [B][17][64]  (s2 buffer, then reused in-place as pooled h3)
//  stats  : 256 floats: sum1[32] sq1[32] sum2[32] sq2[32] scale1[32] shift1[32] scale2[32] shift2[32]
//  W1bf   : bf16 [1088][256]
//  W2bf   : bf16 [256][128]
#define S_BYTES   ((size_t)B_TOTAL * 1088 * 2)      // 142,606,336
#define STATS_OFF S_BYTES
#define W1_OFF    (STATS_OFF + 1024)
#define W2_OFF    (W1_OFF + (size_t)1088*256*2)

__device__ inline float bf2f_lo(uint32 v){ return __uint_as_float(v << 16); }
__device__ inline float bf2f_hi(uint32 v){ return __uint_as_float(v & 0xffff0000u); }
__device__ inline float bfu2f(ushort16 u){ return __uint_as_float(((uint32)u) << 16); }
__device__ inline ushort16 f2bfu(float f){
  union { __hip_bfloat16 h; ushort16 u; } c; c.h = __float2bfloat16(f); return c.u;
}

// encoder + normalized-adjacency aggregate for one batch row, one feature dim e.
// s1[n] = h[n] + invdeg[n] * sum_{j in nbr(n)} h[j],  h[n] = relu(x0*We0 + x1*We1 + be)
__device__ inline void enc_agg(const float* __restrict__ xb,
                               float we0, float we1, float be, float* s1){
  float h[NN];
  #pragma unroll
  for (int n = 0; n < NN; ++n)
    h[n] = fmaxf(fmaf(xb[2*n], we0, fmaf(xb[2*n+1], we1, be)), 0.f);
  #pragma unroll
  for (int n = 0; n < NN; ++n){
    float a = 0.f;
    #pragma unroll
    for (int j = 0; j < 4; ++j) if (j < CNT[n]) a += h[NBR[n][j]];
    s1[n] = fmaf(INVDEG[n], a, h[n]);
  }
}

// per-block stat reduction: per-thread partials -> wave shuffle -> LDS -> global atomics
__device__ inline void reduce_stats(float* sA, float* qA,
                                    float* __restrict__ gSum, float* __restrict__ gSq){
  int t = threadIdx.x;
  #pragma unroll
  for (int n = 0; n < NN; ++n){
    float s = sA[n], q = qA[n];
    #pragma unroll
    for (int off = 32; off > 0; off >>= 1){
      s += __shfl_down(s, off, 64);
      q += __shfl_down(q, off, 64);
    }
    sA[n] = s; qA[n] = q;
  }
  __shared__ float shS[NN], shQ[NN];
  if (t < NN){ shS[t] = 0.f; shQ[t] = 0.f; }
  __syncthreads();
  if ((t & 63) == 0){
    #pragma unroll
    for (int n = 0; n < NN; ++n){ atomicAdd(&shS[n], sA[n]); atomicAdd(&shQ[n], qA[n]); }
  }
  __syncthreads();
  if (t < NN){ atomicAdd(&gSum[t], shS[t]); atomicAdd(&gSq[t], shQ[t]); }
}

// ---- pre-cast MLP weights to bf16 (L2-resident streams in k_mlp) ----
__global__ __launch_bounds__(256) void k_prep(const float* __restrict__ Wp1,
                                              const float* __restrict__ Wp2,
                                              ushort16* __restrict__ W1bf,
                                              ushort16* __restrict__ W2bf){
  int g = blockIdx.x * 256 + threadIdx.x;          // 1216*256 = 311,296
  if (g < 278528)      W1bf[g] = f2bfu(Wp1[g]);
  else                 W2bf[g - 278528] = f2bfu(Wp2[g - 278528]);
}

// ---- pass 1: BN1 statistics over s1 = enc+agg (no big intermediate write) ----
__global__ __launch_bounds__(256,2) void k_stats1(const float* __restrict__ x,
    const float* __restrict__ W_enc, const float* __restrict__ b_enc,
    float* __restrict__ gSum, float* __restrict__ gSq){
  int t = threadIdx.x, e = t & 63, lb = t >> 6;
  float we0 = W_enc[e], we1 = W_enc[64 + e], be = b_enc[e];
  float sA[NN], qA[NN];
  #pragma unroll
  for (int n = 0; n < NN; ++n){ sA[n] = 0.f; qA[n] = 0.f; }
  size_t b0 = (size_t)blockIdx.x * 32;
  for (int it = 0; it < 8; ++it){
    size_t b = b0 + it*4 + lb;
    float s1[NN];
    enc_agg(x + b*34, we0, we1, be, s1);
    #pragma unroll
    for (int n = 0; n < NN; ++n){ sA[n] += s1[n]; qA[n] += s1[n]*s1[n]; }
  }
  reduce_stats(sA, qA, gSum, gSq);
}

// ---- finalize BN stats -> scale/shift ----
__global__ void k_finalize(const float* __restrict__ gSum, const float* __restrict__ gSq,
                           const float* __restrict__ gamma, const float* __restrict__ beta,
                           float* __restrict__ scale, float* __restrict__ shift){
  int n = threadIdx.x;
  if (n < NN){
    const float invC = 1.0f / (float)((size_t)B_TOTAL * 64);
    float mean = gSum[n] * invC;
    float var  = gSq[n]  * invC - mean*mean;
    float istd = rsqrtf(var + 1e-5f);
    float sc   = gamma[n] * istd;
    scale[n] = sc;
    shift[n] = fmaf(-mean, sc, beta[n]);
  }
}

// ---- pass 2: recompute enc+agg, BN1, gc1 matmul (W col in 64 VGPRs), relu, agg,
//      write s2 (bf16) and accumulate BN2 stats ----
__global__ __launch_bounds__(256,2) void k_gc1(const float* __restrict__ x,
    const float* __restrict__ W_enc, const float* __restrict__ b_enc,
    const float* __restrict__ Wg, const float* __restrict__ bg,
    const float* __restrict__ scale, const float* __restrict__ shift,
    __hip_bfloat16* __restrict__ S, float* __restrict__ gSum, float* __restrict__ gSq){
  int t = threadIdx.x, e = t & 63, lb = t >> 6;
  __shared__ float sh_hn[4][NN][64];
  __shared__ float sc_s[NN], sf_s[NN];
  if (t < NN){ sc_s[t] = scale[t]; sf_s[t] = shift[t]; }
  float we0 = W_enc[e], we1 = W_enc[64 + e], be = b_enc[e], bge = bg[e];
  float w[64];
  #pragma unroll
  for (int d = 0; d < 64; ++d) w[d] = Wg[d*64 + e];   // column e of W_gc1, in registers
  float sA[NN], qA[NN];
  #pragma unroll
  for (int n = 0; n < NN; ++n){ sA[n] = 0.f; qA[n] = 0.f; }
  size_t b0 = (size_t)blockIdx.x * 32;
  __syncthreads();
  for (int it = 0; it < 8; ++it){
    size_t b = b0 + it*4 + lb;
    float s1[NN];
    enc_agg(x + b*34, we0, we1, be, s1);
    #pragma unroll
    for (int n = 0; n < NN; ++n) sh_hn[lb][n][e] = fmaf(s1[n], sc_s[n], sf_s[n]);
    __syncthreads();
    float h2[NN];
    #pragma unroll
    for (int n = 0; n < NN; ++n){
      float a = bge;
      const float4* hp = (const float4*)(&sh_hn[lb][n][0]);
      #pragma unroll
      for (int d4 = 0; d4 < 16; ++d4){
        float4 v = hp[d4];
        a = fmaf(v.x, w[4*d4+0], a); a = fmaf(v.y, w[4*d4+1], a);
        a = fmaf(v.z, w[4*d4+2], a); a = fmaf(v.w, w[4*d4+3], a);
      }
      h2[n] = fmaxf(a, 0.f);
    }
    __syncthreads();
    #pragma unroll
    for (int n = 0; n < NN; ++n){
      float agg = 0.f;
      #pragma unroll
      for (int j = 0; j < 4; ++j) if (j < CNT[n]) agg += h2[NBR[n][j]];
      float s2 = fmaf(INVDEG[n], agg, h2[n]);
      __hip_bfloat16 hb = __float2bfloat16(s2);
      S[b*1088 + n*64 + e] = hb;
      float sr = __bfloat162float(hb);              // stats on rounded value = what pass 3 sees
      sA[n] += sr; qA[n] += sr*sr;
    }
  }
  reduce_stats(sA, qA, gSum, gSq);
}

// ---- pass 3a: BN2 + gc2 matmul + relu, in-place S -> pooled h3 (bf16) ----
__global__ __launch_bounds__(256,2) void k_gc2(
    const float* __restrict__ Wg, const float* __restrict__ bg,
    const float* __restrict__ scale, const float* __restrict__ shift,
    __hip_bfloat16* S){
  int t = threadIdx.x, e = t & 63, lb = t >> 6;
  __shared__ float sh_hn[4][NN][64];
  __shared__ float sc_s[NN], sf_s[NN];
  if (t < NN){ sc_s[t] = scale[t]; sf_s[t] = shift[t]; }
  float bge = bg[e];
  float w[64];
  #pragma unroll
  for (int d = 0; d < 64; ++d) w[d] = Wg[d*64 + e];
  size_t b0 = (size_t)blockIdx.x * 32;
  __syncthreads();
  for (int it = 0; it < 8; ++it){
    size_t b = b0 + it*4 + lb;
    #pragma unroll
    for (int n = 0; n < NN; ++n){
      float v = __bfloat162float(S[b*1088 + n*64 + e]);
      sh_hn[lb][n][e] = fmaf(v, sc_s[n], sf_s[n]);
    }
    __syncthreads();
    float h3[NN];
    #pragma unroll
    for (int n = 0; n < NN; ++n){
      float a = bge;
      const float4* hp = (const float4*)(&sh_hn[lb][n][0]);
      #pragma unroll
      for (int d4 = 0; d4 < 16; ++d4){
        float4 v = hp[d4];
        a = fmaf(v.x, w[4*d4+0], a); a = fmaf(v.y, w[4*d4+1], a);
        a = fmaf(v.z, w[4*d4+2], a); a = fmaf(v.w, w[4*d4+3], a);
      }
      h3[n] = fmaxf(a, 0.f);
    }
    __syncthreads();
    #pragma unroll
    for (int n = 0; n < NN; ++n)
      S[b*1088 + n*64 + e] = __float2bfloat16(h3[n]);
  }
}

// ---- pass 3b: pooled MLP + L2 normalize.
// 8 batch rows per block. pooled staged transposed fp32 in LDS; z built via
// k-split across the 4 waves with LDS fp32 atomics; p2 + norm fused epilogue.
__global__ __launch_bounds__(256,2) void k_mlp(const __hip_bfloat16* __restrict__ P,
    const ushort16* __restrict__ W1bf, const float* __restrict__ b_p1,
    const ushort16* __restrict__ W2bf, const float* __restrict__ b_p2,
    float* __restrict__ out){
  __shared__ float poolT[1088][8];   // [k][b]  34,816 B
  __shared__ float z_sh[8][256];     //          8,192 B
  int t = threadIdx.x;
  size_t b0 = (size_t)blockIdx.x * 8;

  // phase A: load 8 pooled rows (bf16) -> transposed fp32; zero z_sh
  {
    const uint32* Pw = (const uint32*)(P + b0*1088);   // 4352 dwords
    #pragma unroll
    for (int r = 0; r < 17; ++r){
      int i = t + r*256;
      uint32 v = Pw[i];
      int b  = i / 544;
      int k2 = i - b*544;
      poolT[2*k2  ][b] = bf2f_lo(v);
      poolT[2*k2+1][b] = bf2f_hi(v);
    }
    for (int i = t; i < 2048; i += 256) ((float*)z_sh)[i] = 0.f;
  }
  __syncthreads();

  // phase B: z[b][j] partials; wave g covers k in [g*272, g*272+272), thread owns j = 4*jj..+3
  {
    int jj = t & 63, g = t >> 6;
    float acc[8][4];
    #pragma unroll
    for (int b = 0; b < 8; ++b){
      #pragma unroll
      for (int m = 0; m < 4; ++m) acc[b][m] = 0.f;
    }
    int k0 = g * 272;
    for (int k = k0; k < k0 + 272; ++k){
      uint2 wv = *(const uint2*)(W1bf + (size_t)k*256 + 4*jj);
      float wf[4] = { bf2f_lo(wv.x), bf2f_hi(wv.x), bf2f_lo(wv.y), bf2f_hi(wv.y) };
      float4 p0 = *(const float4*)&poolT[k][0];
      float4 p1 = *(const float4*)&poolT[k][4];
      float pv[8] = { p0.x, p0.y, p0.z, p0.w, p1.x, p1.y, p1.z, p1.w };
      #pragma unroll
      for (int b = 0; b < 8; ++b){
        #pragma unroll
        for (int m = 0; m < 4; ++m) acc[b][m] = fmaf(pv[b], wf[m], acc[b][m]);
      }
    }
    #pragma unroll
    for (int b = 0; b < 8; ++b){
      #pragma unroll
      for (int m = 0; m < 4; ++m) atomicAdd(&z_sh[b][4*jj + m], acc[b][m]);
    }
  }
  __syncthreads();
  // bias + relu
  for (int i = t; i < 2048; i += 256){
    int b = i >> 8, j = i & 255;
    z_sh[b][j] = fmaxf(z_sh[b][j] + b_p1[j], 0.f);
  }
  __syncthreads();

  // phase C: emb = z @ W_p2 + b_p2; L2-normalize per row. wave wv owns b = 2*wv..2*wv+1
  {
    int e = t & 63, wv = t >> 6;
    float accA[2] = {0.f, 0.f}, accB[2] = {0.f, 0.f};
    for (int j4 = 0; j4 < 64; ++j4){
      float wA[4], wB[4];
      #pragma unroll
      for (int m = 0; m < 4; ++m){
        int j = 4*j4 + m;
        wA[m] = bfu2f(W2bf[j*128 + e]);
        wB[m] = bfu2f(W2bf[j*128 + 64 + e]);
      }
      #pragma unroll
      for (int bb = 0; bb < 2; ++bb){
        float4 zv = *(const float4*)&z_sh[2*wv + bb][4*j4];
        accA[bb] = fmaf(zv.x, wA[0], fmaf(zv.y, wA[1], fmaf(zv.z, wA[2], fmaf(zv.w, wA[3], accA[bb]))));
        accB[bb] = fmaf(zv.x, wB[0], fmaf(zv.y, wB[1], fmaf(zv.z, wB[2], fmaf(zv.w, wB[3], accB[bb]))));
      }
    }
    float bpA = b_p2[e], bpB = b_p2[64 + e];
    #pragma unroll
    for (int bb = 0; bb < 2; ++bb){
      float vA = accA[bb] + bpA, vB = accB[bb] + bpB;
      float ss = vA*vA + vB*vB;
      #pragma unroll
      for (int m = 1; m < 64; m <<= 1) ss += __shfl_xor(ss, m, 64);
      float inv = 1.0f / fmaxf(sqrtf(ss), 1e-12f);
      size_t ob = (b0 + 2*wv + bb) * 128;
      out[ob + e]      = vA * inv;
      out[ob + 64 + e] = vB * inv;
    }
  }
}

extern "C" void kernel_launch(void* const* d_in, const int* in_sizes, int n_in,
                              void* d_out, int out_size, void* d_ws, size_t ws_size,
                              hipStream_t stream) {
  const float* x     = (const float*)d_in[0];
  const float* W_enc = (const float*)d_in[1];
  const float* b_enc = (const float*)d_in[2];
  const float* W_gc1 = (const float*)d_in[3];
  const float* b_gc1 = (const float*)d_in[4];
  const float* W_gc2 = (const float*)d_in[5];
  const float* b_gc2 = (const float*)d_in[6];
  const float* gamma1= (const float*)d_in[7];
  const float* beta1 = (const float*)d_in[8];
  const float* gamma2= (const float*)d_in[9];
  const float* beta2 = (const float*)d_in[10];
  const float* W_p1  = (const float*)d_in[11];
  const float* b_p1  = (const float*)d_in[12];
  const float* W_p2  = (const float*)d_in[13];
  const float* b_p2  = (const float*)d_in[14];
  float* out = (float*)d_out;

  char* ws = (char*)d_ws;
  __hip_bfloat16* S = (__hip_bfloat16*)ws;
  float*    stats = (float*)(ws + STATS_OFF);
  ushort16* W1bf  = (ushort16*)(ws + W1_OFF);
  ushort16* W2bf  = (ushort16*)(ws + W2_OFF);

  hipMemsetAsync(stats, 0, 512, stream);  // zero sum1/sq1/sum2/sq2

  k_prep<<<1216, 256, 0, stream>>>(W_p1, W_p2, W1bf, W2bf);
  k_stats1<<<2048, 256, 0, stream>>>(x, W_enc, b_enc, stats + 0, stats + 32);
  k_finalize<<<1, 32, 0, stream>>>(stats + 0, stats + 32, gamma1, beta1, stats + 128, stats + 160);
  k_gc1<<<2048, 256, 0, stream>>>(x, W_enc, b_enc, W_gc1, b_gc1,
                                  stats + 128, stats + 160, S, stats + 64, stats + 96);
  k_finalize<<<1, 32, 0, stream>>>(stats + 64, stats + 96, gamma2, beta2, stats + 192, stats + 224);
  k_gc2<<<2048, 256, 0, stream>>>(W_gc2, b_gc2, stats + 192, stats + 224, S);
  k_mlp<<<8192, 256, 0, stream>>>(S, W1bf, b_p1, W2bf, b_p2, out);
}

// Round 3
// 744.305 us; speedup vs baseline: 2.0494x; 2.0494x over previous
//
#include <hip/hip_runtime.h>
#include <hip/hip_bf16.h>

typedef unsigned int  uint32;
typedef unsigned short ushort16;

#define B_TOTAL 65536
#define NN 17

typedef __bf16 bf16x8 __attribute__((ext_vector_type(8)));
typedef float  f32x4  __attribute__((ext_vector_type(4)));

// ---- fixed normalized adjacency (from EDGES in the reference) ----
static constexpr int   CNT[NN]    = {2,0,0,0,0,4,4,2,2,1,1,3,3,2,2,1,1};
static constexpr int   NBR[NN][4] = {
  {5,6,0,0},{0,0,0,0},{0,0,0,0},{0,0,0,0},{0,0,0,0},
  {7,6,11,0},{8,5,12,0},{5,9,0,0},{6,10,0,0},{7,0,0,0},{8,0,0,0},
  {5,12,13,0},{6,11,14,0},{11,15,0,0},{12,16,0,0},{13,0,0,0},{14,0,0,0}};
static constexpr float INVDEG[NN] = {0.5f,0.f,0.f,0.f,0.f,0.25f,0.25f,0.5f,0.5f,1.f,1.f,
  0.33333333333333333f,0.33333333333333333f,0.5f,0.5f,1.f,1.f};

// ---- workspace layout (bytes) ----
#define S_BYTES   ((size_t)B_TOTAL * 1088 * 2)
#define STATS_OFF S_BYTES
#define W1_OFF    (STATS_OFF + 1024)
#define W2_OFF    (W1_OFF + (size_t)1088*256*2)

__device__ inline ushort16 f2bfu(float f){
  union { __hip_bfloat16 h; ushort16 u; } c; c.h = __float2bfloat16(f); return c.u;
}

__device__ inline f32x4 MFMA(bf16x8 a, bf16x8 b, f32x4 c){
  return __builtin_amdgcn_mfma_f32_16x16x32_bf16(a, b, c, 0, 0, 0);
}

// encoder + normalized-adjacency aggregate for one batch row, one feature dim e.
__device__ inline void enc_agg(const float* __restrict__ xb,
                               float we0, float we1, float be, float* s1){
  float h[NN];
  #pragma unroll
  for (int n = 0; n < NN; ++n)
    h[n] = fmaxf(fmaf(xb[2*n], we0, fmaf(xb[2*n+1], we1, be)), 0.f);
  #pragma unroll
  for (int n = 0; n < NN; ++n){
    float a = 0.f;
    #pragma unroll
    for (int j = 0; j < 4; ++j) if (j < CNT[n]) a += h[NBR[n][j]];
    s1[n] = fmaf(INVDEG[n], a, h[n]);
  }
}

__device__ inline void reduce_stats(float* sA, float* qA,
                                    float* __restrict__ gSum, float* __restrict__ gSq){
  int t = threadIdx.x;
  #pragma unroll
  for (int n = 0; n < NN; ++n){
    float s = sA[n], q = qA[n];
    #pragma unroll
    for (int off = 32; off > 0; off >>= 1){
      s += __shfl_down(s, off, 64);
      q += __shfl_down(q, off, 64);
    }
    sA[n] = s; qA[n] = q;
  }
  __shared__ float shS[NN], shQ[NN];
  if (t < NN){ shS[t] = 0.f; shQ[t] = 0.f; }
  __syncthreads();
  if ((t & 63) == 0){
    #pragma unroll
    for (int n = 0; n < NN; ++n){ atomicAdd(&shS[n], sA[n]); atomicAdd(&shQ[n], qA[n]); }
  }
  __syncthreads();
  if (t < NN){ atomicAdd(&gSum[t], shS[t]); atomicAdd(&gSq[t], shQ[t]); }
}

// ---- pre-cast + TRANSPOSE MLP weights to bf16 fragment-friendly layout ----
__global__ __launch_bounds__(256) void k_prep(const float* __restrict__ Wp1,
                                              const float* __restrict__ Wp2,
                                              ushort16* __restrict__ W1T,
                                              ushort16* __restrict__ W2T){
  int g = blockIdx.x * 256 + threadIdx.x;          // 1216*256 = 311,296
  if (g < 278528){
    int n = g / 1088, k = g - n*1088;              // W1T[n][k] = W_p1[k][n]
    W1T[g] = f2bfu(Wp1[(size_t)k*256 + n]);
  } else {
    int h = g - 278528;
    int e = h >> 8, k = h & 255;                   // W2T[e][k] = W_p2[k][e]
    W2T[h] = f2bfu(Wp2[(size_t)k*128 + e]);
  }
}

// ---- pass 1: BN1 statistics over s1 = enc+agg ----
__global__ __launch_bounds__(256,2) void k_stats1(const float* __restrict__ x,
    const float* __restrict__ W_enc, const float* __restrict__ b_enc,
    float* __restrict__ gSum, float* __restrict__ gSq){
  int t = threadIdx.x, e = t & 63, lb = t >> 6;
  float we0 = W_enc[e], we1 = W_enc[64 + e], be = b_enc[e];
  float sA[NN], qA[NN];
  #pragma unroll
  for (int n = 0; n < NN; ++n){ sA[n] = 0.f; qA[n] = 0.f; }
  size_t b0 = (size_t)blockIdx.x * 32;
  for (int it = 0; it < 8; ++it){
    size_t b = b0 + it*4 + lb;
    float s1[NN];
    enc_agg(x + b*34, we0, we1, be, s1);
    #pragma unroll
    for (int n = 0; n < NN; ++n){ sA[n] += s1[n]; qA[n] += s1[n]*s1[n]; }
  }
  reduce_stats(sA, qA, gSum, gSq);
}

__global__ void k_finalize(const float* __restrict__ gSum, const float* __restrict__ gSq,
                           const float* __restrict__ gamma, const float* __restrict__ beta,
                           float* __restrict__ scale, float* __restrict__ shift){
  int n = threadIdx.x;
  if (n < NN){
    const float invC = 1.0f / (float)((size_t)B_TOTAL * 64);
    float mean = gSum[n] * invC;
    float var  = gSq[n]  * invC - mean*mean;
    float istd = rsqrtf(var + 1e-5f);
    float sc   = gamma[n] * istd;
    scale[n] = sc;
    shift[n] = fmaf(-mean, sc, beta[n]);
  }
}

// ---- pass 2: enc+agg, BN1, gc1 matmul, relu, agg -> S (bf16) + BN2 stats ----
__global__ __launch_bounds__(256,2) void k_gc1(const float* __restrict__ x,
    const float* __restrict__ W_enc, const float* __restrict__ b_enc,
    const float* __restrict__ Wg, const float* __restrict__ bg,
    const float* __restrict__ scale, const float* __restrict__ shift,
    __hip_bfloat16* __restrict__ S, float* __restrict__ gSum, float* __restrict__ gSq){
  int t = threadIdx.x, e = t & 63, lb = t >> 6;
  __shared__ float sh_hn[4][NN][64];
  __shared__ float sc_s[NN], sf_s[NN];
  if (t < NN){ sc_s[t] = scale[t]; sf_s[t] = shift[t]; }
  float we0 = W_enc[e], we1 = W_enc[64 + e], be = b_enc[e], bge = bg[e];
  float w[64];
  #pragma unroll
  for (int d = 0; d < 64; ++d) w[d] = Wg[d*64 + e];
  float sA[NN], qA[NN];
  #pragma unroll
  for (int n = 0; n < NN; ++n){ sA[n] = 0.f; qA[n] = 0.f; }
  size_t b0 = (size_t)blockIdx.x * 32;
  __syncthreads();
  for (int it = 0; it < 8; ++it){
    size_t b = b0 + it*4 + lb;
    float s1[NN];
    enc_agg(x + b*34, we0, we1, be, s1);
    #pragma unroll
    for (int n = 0; n < NN; ++n) sh_hn[lb][n][e] = fmaf(s1[n], sc_s[n], sf_s[n]);
    __syncthreads();
    float h2[NN];
    #pragma unroll
    for (int n = 0; n < NN; ++n){
      float a = bge;
      const float4* hp = (const float4*)(&sh_hn[lb][n][0]);
      #pragma unroll
      for (int d4 = 0; d4 < 16; ++d4){
        float4 v = hp[d4];
        a = fmaf(v.x, w[4*d4+0], a); a = fmaf(v.y, w[4*d4+1], a);
        a = fmaf(v.z, w[4*d4+2], a); a = fmaf(v.w, w[4*d4+3], a);
      }
      h2[n] = fmaxf(a, 0.f);
    }
    __syncthreads();
    #pragma unroll
    for (int n = 0; n < NN; ++n){
      float agg = 0.f;
      #pragma unroll
      for (int j = 0; j < 4; ++j) if (j < CNT[n]) agg += h2[NBR[n][j]];
      float s2 = fmaf(INVDEG[n], agg, h2[n]);
      __hip_bfloat16 hb = __float2bfloat16(s2);
      S[b*1088 + n*64 + e] = hb;
      float sr = __bfloat162float(hb);
      sA[n] += sr; qA[n] += sr*sr;
    }
  }
  reduce_stats(sA, qA, gSum, gSq);
}

// ---- pass 3a: BN2 + gc2 matmul + relu, in-place S -> pooled h3 (bf16) ----
__global__ __launch_bounds__(256,2) void k_gc2(
    const float* __restrict__ Wg, const float* __restrict__ bg,
    const float* __restrict__ scale, const float* __restrict__ shift,
    __hip_bfloat16* S){
  int t = threadIdx.x, e = t & 63, lb = t >> 6;
  __shared__ float sh_hn[4][NN][64];
  __shared__ float sc_s[NN], sf_s[NN];
  if (t < NN){ sc_s[t] = scale[t]; sf_s[t] = shift[t]; }
  float bge = bg[e];
  float w[64];
  #pragma unroll
  for (int d = 0; d < 64; ++d) w[d] = Wg[d*64 + e];
  size_t b0 = (size_t)blockIdx.x * 32;
  __syncthreads();
  for (int it = 0; it < 8; ++it){
    size_t b = b0 + it*4 + lb;
    #pragma unroll
    for (int n = 0; n < NN; ++n){
      float v = __bfloat162float(S[b*1088 + n*64 + e]);
      sh_hn[lb][n][e] = fmaf(v, sc_s[n], sf_s[n]);
    }
    __syncthreads();
    float h3[NN];
    #pragma unroll
    for (int n = 0; n < NN; ++n){
      float a = bge;
      const float4* hp = (const float4*)(&sh_hn[lb][n][0]);
      #pragma unroll
      for (int d4 = 0; d4 < 16; ++d4){
        float4 v = hp[d4];
        a = fmaf(v.x, w[4*d4+0], a); a = fmaf(v.y, w[4*d4+1], a);
        a = fmaf(v.z, w[4*d4+2], a); a = fmaf(v.w, w[4*d4+3], a);
      }
      h3[n] = fmaxf(a, 0.f);
    }
    __syncthreads();
    #pragma unroll
    for (int n = 0; n < NN; ++n)
      S[b*1088 + n*64 + e] = __float2bfloat16(h3[n]);
  }
}

// ---- pass 3b: MFMA pooled MLP + L2 normalize ----
// z^T = W1T(256x1088) @ P^T(1088x128), then emb^T = W2T(128x256) @ z^T.
// Block: 4 waves, 128 batch rows, full N=256. 16x16x32 bf16 MFMA.
// LDS: Pbuf 2x8KB @0, W1buf 2x16KB @16K (double-buffered staging);
//      z (bf16, XOR-swizzled) 64KB aliased over the whole arena afterwards.
__global__ __launch_bounds__(256,2) void k_mlp(const ushort16* __restrict__ S,
    const ushort16* __restrict__ W1T, const float* __restrict__ b_p1,
    const ushort16* __restrict__ W2T, const float* __restrict__ b_p2,
    float* __restrict__ out){
  __shared__ __align__(16) char smem[65536];
  const int t = threadIdx.x;
  const int L = t & 63, w = t >> 6;
  const int lo = L & 15, q = L >> 4;
  const size_t b0 = (size_t)blockIdx.x * 128;
  const char* Sb  = (const char*)S;
  const char* W1b = (const char*)W1T;
  const char* W2b = (const char*)W2T;

  f32x4 acc[16][2];
  #pragma unroll
  for (int nt = 0; nt < 16; ++nt){ acc[nt][0] = (f32x4)0.f; acc[nt][1] = (f32x4)0.f; }

  uint4 pr0, pr1, wr0, wr1, wr2, wr3;
  const int rowP = t >> 2,            partP = t & 3;      // P: idx = i*256+t
  const int rowP2 = (256 + t) >> 2,   partP2 = t & 3;
  auto loadG = [&](int ks){
    size_t kb = (size_t)ks * 64;
    pr0 = *(const uint4*)(Sb + (b0 + rowP )*2176 + kb + partP *16);
    pr1 = *(const uint4*)(Sb + (b0 + rowP2)*2176 + kb + partP2*16);
    wr0 = *(const uint4*)(W1b + (size_t)((  0 + t) >> 2)*2176 + kb + partP*16);
    wr1 = *(const uint4*)(W1b + (size_t)((256 + t) >> 2)*2176 + kb + partP*16);
    wr2 = *(const uint4*)(W1b + (size_t)((512 + t) >> 2)*2176 + kb + partP*16);
    wr3 = *(const uint4*)(W1b + (size_t)((768 + t) >> 2)*2176 + kb + partP*16);
  };
  auto writeL = [&](int buf){
    char* Pb = smem + (buf ? 8192 : 0);
    char* Wb = smem + 16384 + (buf ? 16384 : 0);
    *(uint4*)(Pb + (size_t)t*16)          = pr0;
    *(uint4*)(Pb + (size_t)(256 + t)*16)  = pr1;
    *(uint4*)(Wb + (size_t)t*16)          = wr0;
    *(uint4*)(Wb + (size_t)(256 + t)*16)  = wr1;
    *(uint4*)(Wb + (size_t)(512 + t)*16)  = wr2;
    *(uint4*)(Wb + (size_t)(768 + t)*16)  = wr3;
  };

  loadG(0); writeL(0);
  __syncthreads();
  #pragma unroll 1
  for (int ks = 0; ks < 34; ++ks){
    const int cur = ks & 1;
    const char* Pb = smem + (cur ? 8192 : 0);
    const char* Wb = smem + 16384 + (cur ? 16384 : 0);
    if (ks < 33) loadG(ks + 1);
    bf16x8 pf0 = *(const bf16x8*)(Pb + (w*32 +  0 + lo)*64 + q*16);
    bf16x8 pf1 = *(const bf16x8*)(Pb + (w*32 + 16 + lo)*64 + q*16);
    #pragma unroll
    for (int nt = 0; nt < 16; ++nt){
      bf16x8 wf = *(const bf16x8*)(Wb + (nt*16 + lo)*64 + q*16);
      acc[nt][0] = MFMA(wf, pf0, acc[nt][0]);
      acc[nt][1] = MFMA(wf, pf1, acc[nt][1]);
    }
    if (ks < 33) writeL(cur ^ 1);
    __syncthreads();
  }

  // epilogue 1: z = relu(z^T + b_p1) -> LDS bf16 [b][256], 8B-granule XOR swizzle by (b&7)
  #pragma unroll
  for (int nt = 0; nt < 16; ++nt){
    float4 bias = *(const float4*)&b_p1[nt*16 + q*4];
    #pragma unroll
    for (int bt = 0; bt < 2; ++bt){
      int b = w*32 + bt*16 + lo;
      f32x4 v = acc[nt][bt];
      float z0 = fmaxf(v.x + bias.x, 0.f), z1 = fmaxf(v.y + bias.y, 0.f);
      float z2 = fmaxf(v.z + bias.z, 0.f), z3 = fmaxf(v.w + bias.w, 0.f);
      uint32 lo32 = (uint32)f2bfu(z0) | ((uint32)f2bfu(z1) << 16);
      uint32 hi32 = (uint32)f2bfu(z2) | ((uint32)f2bfu(z3) << 16);
      int nbyte = (nt*16 + q*4) * 2;
      int addr = b*512 + (nbyte ^ ((b & 7) << 4));
      *(uint2*)(smem + addr) = make_uint2(lo32, hi32);
    }
  }
  __syncthreads();

  // phase 2: emb^T = W2T @ z^T  (K=256, 8 k-steps)
  f32x4 acc2[8][2];
  #pragma unroll
  for (int et = 0; et < 8; ++et){ acc2[et][0] = (f32x4)0.f; acc2[et][1] = (f32x4)0.f; }
  #pragma unroll 1
  for (int ks = 0; ks < 8; ++ks){
    bf16x8 zf0, zf1;
    {
      int b = w*32 + lo;
      int kb = ks*64 + q*16;
      zf0 = *(const bf16x8*)(smem + b*512 + (kb ^ ((b & 7) << 4)));
      b = w*32 + 16 + lo;
      zf1 = *(const bf16x8*)(smem + b*512 + (kb ^ ((b & 7) << 4)));
    }
    #pragma unroll
    for (int et = 0; et < 8; ++et){
      bf16x8 wf = *(const bf16x8*)(W2b + (et*16 + lo)*512 + ks*64 + q*16);
      acc2[et][0] = MFMA(wf, zf0, acc2[et][0]);
      acc2[et][1] = MFMA(wf, zf1, acc2[et][1]);
    }
  }

  // epilogue 2: + b_p2, L2-normalize rows (b), float4 stores
  #pragma unroll
  for (int bt = 0; bt < 2; ++bt){
    int b = w*32 + bt*16 + lo;
    float4 vv[8];
    float ss = 0.f;
    #pragma unroll
    for (int et = 0; et < 8; ++et){
      float4 bias = *(const float4*)&b_p2[et*16 + q*4];
      f32x4 a = bt ? acc2[et][1] : acc2[et][0];
      vv[et].x = a.x + bias.x; vv[et].y = a.y + bias.y;
      vv[et].z = a.z + bias.z; vv[et].w = a.w + bias.w;
      ss += vv[et].x*vv[et].x + vv[et].y*vv[et].y + vv[et].z*vv[et].z + vv[et].w*vv[et].w;
    }
    ss += __shfl_xor(ss, 16, 64);
    ss += __shfl_xor(ss, 32, 64);
    float inv = 1.0f / fmaxf(sqrtf(ss), 1e-12f);
    float* op = out + (b0 + b)*128;
    #pragma unroll
    for (int et = 0; et < 8; ++et){
      float4 o; o.x = vv[et].x*inv; o.y = vv[et].y*inv; o.z = vv[et].z*inv; o.w = vv[et].w*inv;
      *(float4*)(op + et*16 + q*4) = o;
    }
  }
}

extern "C" void kernel_launch(void* const* d_in, const int* in_sizes, int n_in,
                              void* d_out, int out_size, void* d_ws, size_t ws_size,
                              hipStream_t stream) {
  const float* x     = (const float*)d_in[0];
  const float* W_enc = (const float*)d_in[1];
  const float* b_enc = (const float*)d_in[2];
  const float* W_gc1 = (const float*)d_in[3];
  const float* b_gc1 = (const float*)d_in[4];
  const float* W_gc2 = (const float*)d_in[5];
  const float* b_gc2 = (const float*)d_in[6];
  const float* gamma1= (const float*)d_in[7];
  const float* beta1 = (const float*)d_in[8];
  const float* gamma2= (const float*)d_in[9];
  const float* beta2 = (const float*)d_in[10];
  const float* W_p1  = (const float*)d_in[11];
  const float* b_p1  = (const float*)d_in[12];
  const float* W_p2  = (const float*)d_in[13];
  const float* b_p2  = (const float*)d_in[14];
  float* out = (float*)d_out;

  char* ws = (char*)d_ws;
  __hip_bfloat16* S = (__hip_bfloat16*)ws;
  float*    stats = (float*)(ws + STATS_OFF);
  ushort16* W1T   = (ushort16*)(ws + W1_OFF);
  ushort16* W2T   = (ushort16*)(ws + W2_OFF);

  (void)hipMemsetAsync(stats, 0, 512, stream);

  k_prep<<<1216, 256, 0, stream>>>(W_p1, W_p2, W1T, W2T);
  k_stats1<<<2048, 256, 0, stream>>>(x, W_enc, b_enc, stats + 0, stats + 32);
  k_finalize<<<1, 32, 0, stream>>>(stats + 0, stats + 32, gamma1, beta1, stats + 128, stats + 160);
  k_gc1<<<2048, 256, 0, stream>>>(x, W_enc, b_enc, W_gc1, b_gc1,
                                  stats + 128, stats + 160, S, stats + 64, stats + 96);
  k_finalize<<<1, 32, 0, stream>>>(stats + 64, stats + 96, gamma2, beta2, stats + 192, stats + 224);
  k_gc2<<<2048, 256, 0, stream>>>(W_gc2, b_gc2, stats + 192, stats + 224, S);
  k_mlp<<<512, 256, 0, stream>>>((const ushort16*)S, W1T, b_p1, (const ushort16*)W2T, b_p2, out);
}